// Round 7
// baseline (163.585 us; speedup 1.0000x reference)
//
#include <hip/hip_runtime.h>

namespace {

typedef _Float16 v8h __attribute__((ext_vector_type(8)));
typedef float    v4f __attribute__((ext_vector_type(4)));

constexpr int NMEL = 128;
constexpr int ND   = 64;
constexpr int NK   = 128;
constexpr int NTOK = 32 * 4096;          // 131072
constexpr int TPB  = 128;                // tokens per block (4 waves x 32)
constexpr int GRID = NTOK / TPB;         // 1024

// ---------------------------------------------------------------------------
// precomp: all token-independent tables into d_ws.
//   E[j][m] = sum_d cb01[j][d]*w_in[d][m] -> f16 hi/lo, stored SWIZZLED in
//   MFMA-fragment order: per (stage s, c-block c): 8KB = [hi kk0..3][lo kk0..3]
//   of 1KB each; element lane*16B + e*2B holds
//   E[s*128 + c*16 + (lane&15)][kk*32 + (lane>>4)*8 + e].
//   nh[j] = 0.5||c_j||^2 - b_in.c_j ; G[a][b] = cb0_a.cb1_b ;
//   Dec0[a][m] = cb0_a.w_out_m + b_out_m ; Dec1[b][m] = cb1_b.w_out_m.
// ---------------------------------------------------------------------------
__global__ __launch_bounds__(256) void precomp(
    const float* __restrict__ w_in, const float* __restrict__ b_in,
    const float* __restrict__ cb0, const float* __restrict__ cb1,
    const float* __restrict__ w_out, const float* __restrict__ b_out,
    float* __restrict__ dec0, float* __restrict__ dec1,
    float* __restrict__ G, float* __restrict__ nh,
    _Float16* __restrict__ E_swz) {
  const int j = blockIdx.x;          // 0..255
  const int tid = threadIdx.x;
  const float* __restrict__ crow = (j < NK) ? (cb0 + j * ND) : (cb1 + (j - NK) * ND);

  if (tid < NMEL) {
    const int m = tid;
    float e = 0.f;
#pragma unroll 8
    for (int d = 0; d < ND; ++d) e += crow[d] * w_in[d * NMEL + m];
    const _Float16 hi = (_Float16)e;
    const _Float16 lo = (_Float16)(e - (float)hi);
    const int s = j >> 7, jj = j & 127, c = jj >> 4, mr = jj & 15;
    const int kk = m >> 5, q = (m >> 3) & 3, ei = m & 7;
    const int lane = q * 16 + mr;
    const size_t base = ((((size_t)s * 8 + c) * 8) + kk) * 512;  // h=0 chunk (halves)
    E_swz[base + lane * 8 + ei] = hi;
    E_swz[base + 2048 + lane * 8 + ei] = lo;                     // h=1 chunk
  } else {
    const int m = tid - NMEL;
    const float4* wr = (const float4*)(w_out + m * ND);
    const float4* cr4 = (const float4*)crow;
    float a = 0.f;
#pragma unroll
    for (int qq = 0; qq < ND / 4; ++qq) {
      const float4 w4 = wr[qq], c4 = cr4[qq];
      a += c4.x * w4.x + c4.y * w4.y + c4.z * w4.z + c4.w * w4.w;
    }
    if (j < NK) dec0[j * NMEL + m] = a + b_out[m];
    else        dec1[(j - NK) * NMEL + m] = a;
    if (j < NK) {
      const float4* c1r = (const float4*)(cb1 + m * ND);
      float g = 0.f;
#pragma unroll
      for (int qq = 0; qq < ND / 4; ++qq) {
        const float4 c4 = cr4[qq], d4 = c1r[qq];
        g += c4.x * d4.x + c4.y * d4.y + c4.z * d4.z + c4.w * d4.w;
      }
      G[j * NK + m] = g;
    }
  }
  if (tid < 64) {  // whole first wave: nh[j] via butterfly reduce
    const float v = crow[tid];
    float t = 0.5f * v * v - b_in[tid] * v;
#pragma unroll
    for (int d = 1; d < 64; d <<= 1) t += __shfl_xor(t, d);
    if (tid == 0) nh[j] = t;
  }
}

// ---------------------------------------------------------------------------
// main: block = 256 thr (4 waves), 128 tokens (2 tiles of 16 per wave).
// ZERO-BARRIER wave-private pipeline. r0 vs r6 proved occupancy is capped by
// registers (18.6% @64KB LDS == 19.2% @32KB) — LDS is free, block barriers
// convoy all 4 waves and each __syncthreads drains vmcnt(0). So: each wave
// gets a PRIVATE 2 x 8KB double buffer (64 KB total), fills its own next
// c-chunk with global_load_lds, and gates on a counted s_waitcnt vmcnt(8)
// (never 0 — the just-issued next-chunk fill stays in flight). Waves drift
// freely; the SIMD always has a wave in a different phase to issue.
// E refetched 4x/block from L2 (~12 TB/s agg vs 34.5 ceiling; HBM unchanged).
// Math bit-identical to r0/r6. __launch_bounds__(256,2): the only config the
// allocator gives ~124-128 VGPRs (any "4" => 64-VGPR clamp => spill disaster).
// ---------------------------------------------------------------------------
__global__ __launch_bounds__(256, 2) void rvq_main(
    const float* __restrict__ mel,
    const _Float16* __restrict__ E_swz,
    const float* __restrict__ nh,
    const float* __restrict__ G,
    const float* __restrict__ dec0,
    const float* __restrict__ dec1,
    float* __restrict__ out) {
  __shared__ _Float16 sE[4][2][4096];   // 64 KB: per-wave private double buffer
  const int tid = threadIdx.x;
  const int wv = tid >> 6;
  const int ln = tid & 63;
  const int m  = ln & 15;
  const int q  = ln >> 4;

  _Float16* const myb0 = &sE[wv][0][0];
  _Float16* const myb1 = &sE[wv][1][0];

  // fill chunk ch (8 KB = c-block ch&7 of stage ch>>3, hi+lo) into own buffer
  auto FILL = [&](int ch) {
    const char* g = (const char*)E_swz + (size_t)ch * 8192;
    char* l = (char*)((ch & 1) ? myb1 : myb0);
#pragma unroll
    for (int it = 0; it < 8; ++it) {
      __builtin_amdgcn_global_load_lds(
          (const __attribute__((address_space(1))) void*)(g + it * 1024 + (size_t)ln * 16),
          (__attribute__((address_space(3))) void*)(l + it * 1024),
          16, 0, 0);
    }
  };

  FILL(0);

  // ---- A fragments: 2 tiles x 16 tokens, fp32 -> f16 hi+lo (hides fill0;
  //      the compiler's wait for mel also drains the older fill-0 loads) ----
  v8h a_hi[2][4], a_lo[2][4];
#pragma unroll
  for (int t = 0; t < 2; ++t) {
    const int tok0 = blockIdx.x * TPB + wv * 32 + t * 16;
    const float* xr = mel + (size_t)(tok0 + m) * NMEL + q * 8;
#pragma unroll
    for (int kk = 0; kk < 4; ++kk) {
      const float4 x0 = *(const float4*)(xr + kk * 32);
      const float4 x1 = *(const float4*)(xr + kk * 32 + 4);
      const float xs[8] = {x0.x, x0.y, x0.z, x0.w, x1.x, x1.y, x1.z, x1.w};
#pragma unroll
      for (int e = 0; e < 8; ++e) {
        const _Float16 h = (_Float16)xs[e];
        a_hi[t][kk][e] = h;
        a_lo[t][kk][e] = (_Float16)(xs[e] - (float)h);
      }
    }
  }

  FILL(1);

  float nhv[8];
#pragma unroll
  for (int c = 0; c < 8; ++c) nhv[c] = nh[c * 16 + m];

  float bv[2][4];
  int   bi[2][4];
  int   s0i[2][4], s1i[2][4];
  float gc[2][4];

  // one c-block compute from own buffer. stage1 also runs the gc/gn G chain.
  auto COMP = [&](const _Float16* __restrict__ buf, int c, bool stage1) {
    v8h bh[4], bl[4];
#pragma unroll
    for (int kk = 0; kk < 4; ++kk) {
      bh[kk] = *(const v8h*)(buf + kk * 512 + ln * 8);
      bl[kk] = *(const v8h*)(buf + 2048 + kk * 512 + ln * 8);
    }
    float gn[2][4];
    if (stage1 && c < 7) {
#pragma unroll
      for (int t = 0; t < 2; ++t)
#pragma unroll
        for (int i = 0; i < 4; ++i)
          gn[t][i] = G[(size_t)s0i[t][i] * NK + (c + 1) * 16 + m];
    }
    v4f a0 = (v4f){0.f, 0.f, 0.f, 0.f}, a1 = a0;
#pragma unroll
    for (int kk = 0; kk < 4; ++kk) {
      a0 = __builtin_amdgcn_mfma_f32_16x16x32_f16(a_hi[0][kk], bh[kk], a0, 0, 0, 0);
      a1 = __builtin_amdgcn_mfma_f32_16x16x32_f16(a_hi[1][kk], bh[kk], a1, 0, 0, 0);
      a0 = __builtin_amdgcn_mfma_f32_16x16x32_f16(a_lo[0][kk], bh[kk], a0, 0, 0, 0);
      a1 = __builtin_amdgcn_mfma_f32_16x16x32_f16(a_lo[1][kk], bh[kk], a1, 0, 0, 0);
      a0 = __builtin_amdgcn_mfma_f32_16x16x32_f16(a_hi[0][kk], bl[kk], a0, 0, 0, 0);
      a1 = __builtin_amdgcn_mfma_f32_16x16x32_f16(a_hi[1][kk], bl[kk], a1, 0, 0, 0);
    }
    const float nv = nhv[c];
    const int jj = c * 16 + m;
    if (!stage1) {
#pragma unroll
      for (int i = 0; i < 4; ++i) {
        const float s0 = nv - a0[i];
        if (s0 < bv[0][i]) { bv[0][i] = s0; bi[0][i] = jj; }
        const float s1 = nv - a1[i];
        if (s1 < bv[1][i]) { bv[1][i] = s1; bi[1][i] = jj; }
      }
    } else {
#pragma unroll
      for (int i = 0; i < 4; ++i) {
        const float s0 = nv + gc[0][i] - a0[i];
        if (s0 < bv[0][i]) { bv[0][i] = s0; bi[0][i] = jj; }
        const float s1 = nv + gc[1][i] - a1[i];
        if (s1 < bv[1][i]) { bv[1][i] = s1; bi[1][i] = jj; }
      }
      if (c < 7) {
#pragma unroll
        for (int t = 0; t < 2; ++t)
#pragma unroll
          for (int i = 0; i < 4; ++i) gc[t][i] = gn[t][i];
      }
    }
  };

  auto REDUCE = [&](int (&dst)[2][4]) {
#pragma unroll
    for (int d = 1; d < 16; d <<= 1)
#pragma unroll
      for (int t = 0; t < 2; ++t)
#pragma unroll
        for (int i = 0; i < 4; ++i) {
          const float ov = __shfl_xor(bv[t][i], d);
          const int   oi = __shfl_xor(bi[t][i], d);
          if (ov < bv[t][i] || (ov == bv[t][i] && oi < bi[t][i])) { bv[t][i] = ov; bi[t][i] = oi; }
        }
#pragma unroll
    for (int t = 0; t < 2; ++t)
#pragma unroll
      for (int i = 0; i < 4; ++i) dst[t][i] = bi[t][i];
  };

#pragma unroll
  for (int t = 0; t < 2; ++t)
#pragma unroll
    for (int i = 0; i < 4; ++i) { bv[t][i] = 3.4e38f; bi[t][i] = 0; }

  // ---- 16 chunk-steps, NO barriers. Invariant at step ch top: outstanding
  //      VMEM <= F(ch) + F(ch+1); vmcnt(8) forces F(ch) done, keeps F(ch+1).
#pragma unroll
  for (int ch = 0; ch < 16; ++ch) {
    if (ch == 8) {           // stage boundary: reduce, stage-1 constants
      REDUCE(s0i);
#pragma unroll
      for (int c = 0; c < 8; ++c) nhv[c] = nh[NK + c * 16 + m];
#pragma unroll
      for (int t = 0; t < 2; ++t)
#pragma unroll
        for (int i = 0; i < 4; ++i) {
          gc[t][i] = G[(size_t)s0i[t][i] * NK + m];  // c=0
          bv[t][i] = 3.4e38f; bi[t][i] = 0;
        }
    }
    asm volatile("s_waitcnt vmcnt(8)" ::: "memory");
    __builtin_amdgcn_sched_barrier(0);
    COMP((ch & 1) ? myb1 : myb0, ch & 7, ch >= 8);
    if (ch < 14) {
      __builtin_amdgcn_sched_barrier(0);   // pin fill after the MFMA cluster
      FILL(ch + 2);
    }
  }
  REDUCE(s1i);

  // ---- epilogue: out = Dec0[s0] + Dec1[s1] ----
#pragma unroll
  for (int t = 0; t < 2; ++t)
#pragma unroll
    for (int i = 0; i < 4; ++i) {
      const int tok = blockIdx.x * TPB + wv * 32 + t * 16 + q * 4 + i;
      const float4* p0 = (const float4*)(dec0 + (size_t)s0i[t][i] * NMEL + m * 8);
      const float4* p1 = (const float4*)(dec1 + (size_t)s1i[t][i] * NMEL + m * 8);
      float4* o = (float4*)(out + (size_t)tok * NMEL + m * 8);
      const float4 u0 = p0[0], u1 = p0[1], w0 = p1[0], w1 = p1[1];
      float4 r0, r1;
      r0.x = u0.x + w0.x; r0.y = u0.y + w0.y; r0.z = u0.z + w0.z; r0.w = u0.w + w0.w;
      r1.x = u1.x + w1.x; r1.y = u1.y + w1.y; r1.z = u1.z + w1.z; r1.w = u1.w + w1.w;
      o[0] = r0; o[1] = r1;
    }
}

}  // namespace

extern "C" void kernel_launch(void* const* d_in, const int* in_sizes, int n_in,
                              void* d_out, int out_size, void* d_ws, size_t ws_size,
                              hipStream_t stream) {
  const float* mel   = (const float*)d_in[0];
  const float* w_in  = (const float*)d_in[1];
  const float* b_in  = (const float*)d_in[2];
  const float* cb0   = (const float*)d_in[3];
  const float* cb1   = (const float*)d_in[4];
  const float* w_out = (const float*)d_in[5];
  const float* b_out = (const float*)d_in[6];
  float* out = (float*)d_out;

  // ws: dec0 | dec1 | G | nh | E_swz  (64+64+64+1+128 KB ~ 321 KB)
  float* dec0 = (float*)d_ws;
  float* dec1 = dec0 + NK * NMEL;
  float* G    = dec1 + NK * NMEL;
  float* nh   = G + NK * NK;
  _Float16* E_swz = (_Float16*)(nh + 2 * NK);

  hipLaunchKernelGGL(precomp, dim3(2 * NK), dim3(256), 0, stream,
                     w_in, b_in, cb0, cb1, w_out, b_out, dec0, dec1, G, nh, E_swz);
  hipLaunchKernelGGL(rvq_main, dim3(GRID), dim3(256), 0, stream,
                     mel, E_swz, nh, G, dec0, dec1, out);
}

// Round 8
// 155.866 us; speedup vs baseline: 1.0495x; 1.0495x over previous
//
#include <hip/hip_runtime.h>

namespace {

typedef _Float16 v8h __attribute__((ext_vector_type(8)));
typedef float    v4f __attribute__((ext_vector_type(4)));

constexpr int NMEL = 128;
constexpr int ND   = 64;
constexpr int NK   = 128;
constexpr int NTOK = 32 * 4096;          // 131072
constexpr int TPB  = 64;                 // tokens per block (4 waves x 16)
constexpr int GRID = NTOK / TPB;         // 2048 = 8 blocks/CU of work

// ---------------------------------------------------------------------------
// precomp: all token-independent tables into d_ws.
//   E[j][m] = sum_d cb01[j][d]*w_in[d][m] -> f16 hi/lo, stored SWIZZLED in
//   MFMA-fragment order: per (stage s, c-block c): 8KB = [hi kk0..3][lo kk0..3]
//   of 1KB each; element lane*16B + e*2B holds
//   E[s*128 + c*16 + (lane&15)][kk*32 + (lane>>4)*8 + e].
//   nh[j] = 0.5||c_j||^2 - b_in.c_j ; G[a][b] = cb0_a.cb1_b ;
//   Dec0[a][m] = cb0_a.w_out_m + b_out_m ; Dec1[b][m] = cb1_b.w_out_m.
// ---------------------------------------------------------------------------
__global__ __launch_bounds__(256) void precomp(
    const float* __restrict__ w_in, const float* __restrict__ b_in,
    const float* __restrict__ cb0, const float* __restrict__ cb1,
    const float* __restrict__ w_out, const float* __restrict__ b_out,
    float* __restrict__ dec0, float* __restrict__ dec1,
    float* __restrict__ G, float* __restrict__ nh,
    _Float16* __restrict__ E_swz) {
  const int j = blockIdx.x;          // 0..255
  const int tid = threadIdx.x;
  const float* __restrict__ crow = (j < NK) ? (cb0 + j * ND) : (cb1 + (j - NK) * ND);

  if (tid < NMEL) {
    const int m = tid;
    float e = 0.f;
#pragma unroll 8
    for (int d = 0; d < ND; ++d) e += crow[d] * w_in[d * NMEL + m];
    const _Float16 hi = (_Float16)e;
    const _Float16 lo = (_Float16)(e - (float)hi);
    const int s = j >> 7, jj = j & 127, c = jj >> 4, mr = jj & 15;
    const int kk = m >> 5, q = (m >> 3) & 3, ei = m & 7;
    const int lane = q * 16 + mr;
    const size_t base = ((((size_t)s * 8 + c) * 8) + kk) * 512;  // h=0 chunk (halves)
    E_swz[base + lane * 8 + ei] = hi;
    E_swz[base + 2048 + lane * 8 + ei] = lo;                     // h=1 chunk
  } else {
    const int m = tid - NMEL;
    const float4* wr = (const float4*)(w_out + m * ND);
    const float4* cr4 = (const float4*)crow;
    float a = 0.f;
#pragma unroll
    for (int qq = 0; qq < ND / 4; ++qq) {
      const float4 w4 = wr[qq], c4 = cr4[qq];
      a += c4.x * w4.x + c4.y * w4.y + c4.z * w4.z + c4.w * w4.w;
    }
    if (j < NK) dec0[j * NMEL + m] = a + b_out[m];
    else        dec1[(j - NK) * NMEL + m] = a;
    if (j < NK) {
      const float4* c1r = (const float4*)(cb1 + m * ND);
      float g = 0.f;
#pragma unroll
      for (int qq = 0; qq < ND / 4; ++qq) {
        const float4 c4 = cr4[qq], d4 = c1r[qq];
        g += c4.x * d4.x + c4.y * d4.y + c4.z * d4.z + c4.w * d4.w;
      }
      G[j * NK + m] = g;
    }
  }
  if (tid < 64) {  // whole first wave: nh[j] via butterfly reduce
    const float v = crow[tid];
    float t = 0.5f * v * v - b_in[tid] * v;
#pragma unroll
    for (int d = 1; d < 64; d <<= 1) t += __shfl_xor(t, d);
    if (tid == 0) nh[j] = t;
  }
}

// ---------------------------------------------------------------------------
// main: block = 256 thr (4 waves), 64 tokens (ONE 16-token tile per wave).
// Register-diet experiment: r0/r6/r7 proved schedule variants are null and
// occupancy is pinned ~19% (2 waves/SIMD) whenever reported VGPR is 112-128
// (unreported AGPR/transients push the wave-slot tier past 128 -> 2/SIMD;
// r3 at VGPR=64 measured 42%). Halving the per-wave tile count halves
// a-frags/acc/trackers -> expected ~80-90 VGPR -> 4+ waves/SIMD tier.
// Same r6 chunk schedule: 2 x 16KB LDS dbuf, fill(i+1) -> compute(i) -> sync.
// __launch_bounds__(256,2): the only bounds with sane allocator behavior.
// ---------------------------------------------------------------------------
__global__ __launch_bounds__(256, 2) void rvq_main(
    const float* __restrict__ mel,
    const _Float16* __restrict__ E_swz,
    const float* __restrict__ nh,
    const float* __restrict__ G,
    const float* __restrict__ dec0,
    const float* __restrict__ dec1,
    float* __restrict__ out) {
  __shared__ _Float16 sE[2][8192];   // 2 x 16 KB chunk buffers
  const int tid = threadIdx.x;
  const int wv = tid >> 6;
  const int ln = tid & 63;
  const int m  = ln & 15;
  const int q  = ln >> 4;

  // fill chunk ch (16 KB = c-blocks {2ch, 2ch+1} of E, hi+lo) into sE[ch&1]
  auto FILL = [&](int ch) {
    const char* g = (const char*)E_swz + (size_t)ch * 16384;
    char* l = (char*)(&sE[ch & 1][0]);
#pragma unroll
    for (int it = 0; it < 4; ++it) {
      __builtin_amdgcn_global_load_lds(
          (const __attribute__((address_space(1))) void*)(g + it * 4096 + wv * 1024 + ln * 16),
          (__attribute__((address_space(3))) void*)(l + it * 4096 + wv * 1024),
          16, 0, 0);
    }
  };

  FILL(0);

  // ---- A fragments: 1 tile x 16 tokens, fp32 -> f16 hi+lo (hides fill0) --
  v8h a_hi[4], a_lo[4];
  {
    const int tok0 = blockIdx.x * TPB + wv * 16;
    const float* xr = mel + (size_t)(tok0 + m) * NMEL + q * 8;
#pragma unroll
    for (int kk = 0; kk < 4; ++kk) {
      const float4 x0 = *(const float4*)(xr + kk * 32);
      const float4 x1 = *(const float4*)(xr + kk * 32 + 4);
      const float xs[8] = {x0.x, x0.y, x0.z, x0.w, x1.x, x1.y, x1.z, x1.w};
#pragma unroll
      for (int e = 0; e < 8; ++e) {
        const _Float16 h = (_Float16)xs[e];
        a_hi[kk][e] = h;
        a_lo[kk][e] = (_Float16)(xs[e] - (float)h);
      }
    }
  }

  float nhv[8];
#pragma unroll
  for (int c = 0; c < 8; ++c) nhv[c] = nh[c * 16 + m];

  float bv[4];
  int   bi[4];
  int   s0i[4], s1i[4];
  float gc[4];

  // one 2-c compute step from chunk buffer ch&1. cbase = (ch&3)*2.
  auto COMP = [&](int ch, bool stage1) {
    const _Float16* __restrict__ buf = &sE[ch & 1][0];
    const int cbase = (ch & 3) * 2;
#pragma unroll
    for (int cc = 0; cc < 2; ++cc) {
      const int c = cbase + cc;
      v8h bh[4], bl[4];
#pragma unroll
      for (int kk = 0; kk < 4; ++kk) {
        bh[kk] = *(const v8h*)(buf + cc * 4096 + kk * 512 + ln * 8);
        bl[kk] = *(const v8h*)(buf + cc * 4096 + 2048 + kk * 512 + ln * 8);
      }
      float gn[4];
      if (stage1 && c < 7) {
#pragma unroll
        for (int i = 0; i < 4; ++i)
          gn[i] = G[(size_t)s0i[i] * NK + (c + 1) * 16 + m];
      }
      v4f a0 = (v4f){0.f, 0.f, 0.f, 0.f};
#pragma unroll
      for (int kk = 0; kk < 4; ++kk) {
        a0 = __builtin_amdgcn_mfma_f32_16x16x32_f16(a_hi[kk], bh[kk], a0, 0, 0, 0);
        a0 = __builtin_amdgcn_mfma_f32_16x16x32_f16(a_lo[kk], bh[kk], a0, 0, 0, 0);
        a0 = __builtin_amdgcn_mfma_f32_16x16x32_f16(a_hi[kk], bl[kk], a0, 0, 0, 0);
      }
      const float nv = nhv[c];
      const int jj = c * 16 + m;
      if (!stage1) {
#pragma unroll
        for (int i = 0; i < 4; ++i) {
          const float s0 = nv - a0[i];
          if (s0 < bv[i]) { bv[i] = s0; bi[i] = jj; }
        }
      } else {
#pragma unroll
        for (int i = 0; i < 4; ++i) {
          const float s0 = nv + gc[i] - a0[i];
          if (s0 < bv[i]) { bv[i] = s0; bi[i] = jj; }
        }
        if (c < 7) {
#pragma unroll
          for (int i = 0; i < 4; ++i) gc[i] = gn[i];
        }
      }
    }
  };

  auto REDUCE = [&](int (&dst)[4]) {
#pragma unroll
    for (int d = 1; d < 16; d <<= 1)
#pragma unroll
      for (int i = 0; i < 4; ++i) {
        const float ov = __shfl_xor(bv[i], d);
        const int   oi = __shfl_xor(bi[i], d);
        if (ov < bv[i] || (ov == bv[i] && oi < bi[i])) { bv[i] = ov; bi[i] = oi; }
      }
#pragma unroll
    for (int i = 0; i < 4; ++i) dst[i] = bi[i];
  };

#pragma unroll
  for (int i = 0; i < 4; ++i) { bv[i] = 3.4e38f; bi[i] = 0; }

  __syncthreads();                 // fill0 done

  // ---- stage 0: chunks 0..3 (c = 0..7) ----
  FILL(1); COMP(0, false); __syncthreads();
  FILL(2); COMP(1, false); __syncthreads();
  FILL(3); COMP(2, false); __syncthreads();
  FILL(4); COMP(3, false);
  REDUCE(s0i);
  __syncthreads();                 // fill4 done; buf[1] free

  // ---- stage-1 constants; chunks 4..7 (c = 0..7 of stage 1) ----
#pragma unroll
  for (int c = 0; c < 8; ++c) nhv[c] = nh[NK + c * 16 + m];
#pragma unroll
  for (int i = 0; i < 4; ++i) {
    gc[i] = G[(size_t)s0i[i] * NK + m];  // c=0
    bv[i] = 3.4e38f; bi[i] = 0;
  }

  FILL(5); COMP(4, true); __syncthreads();
  FILL(6); COMP(5, true); __syncthreads();
  FILL(7); COMP(6, true); __syncthreads();
  COMP(7, true);                   // last chunk: no fill, no sync
  REDUCE(s1i);

  // ---- epilogue: out = Dec0[s0] + Dec1[s1] ----
#pragma unroll
  for (int i = 0; i < 4; ++i) {
    const int tok = blockIdx.x * TPB + wv * 16 + q * 4 + i;
    const float4* p0 = (const float4*)(dec0 + (size_t)s0i[i] * NMEL + m * 8);
    const float4* p1 = (const float4*)(dec1 + (size_t)s1i[i] * NMEL + m * 8);
    float4* o = (float4*)(out + (size_t)tok * NMEL + m * 8);
    const float4 u0 = p0[0], u1 = p0[1], w0 = p1[0], w1 = p1[1];
    float4 r0, r1;
    r0.x = u0.x + w0.x; r0.y = u0.y + w0.y; r0.z = u0.z + w0.z; r0.w = u0.w + w0.w;
    r1.x = u1.x + w1.x; r1.y = u1.y + w1.y; r1.z = u1.z + w1.z; r1.w = u1.w + w1.w;
    o[0] = r0; o[1] = r1;
  }
}

}  // namespace

extern "C" void kernel_launch(void* const* d_in, const int* in_sizes, int n_in,
                              void* d_out, int out_size, void* d_ws, size_t ws_size,
                              hipStream_t stream) {
  const float* mel   = (const float*)d_in[0];
  const float* w_in  = (const float*)d_in[1];
  const float* b_in  = (const float*)d_in[2];
  const float* cb0   = (const float*)d_in[3];
  const float* cb1   = (const float*)d_in[4];
  const float* w_out = (const float*)d_in[5];
  const float* b_out = (const float*)d_in[6];
  float* out = (float*)d_out;

  // ws: dec0 | dec1 | G | nh | E_swz  (64+64+64+1+128 KB ~ 321 KB)
  float* dec0 = (float*)d_ws;
  float* dec1 = dec0 + NK * NMEL;
  float* G    = dec1 + NK * NMEL;
  float* nh   = G + NK * NK;
  _Float16* E_swz = (_Float16*)(nh + 2 * NK);

  hipLaunchKernelGGL(precomp, dim3(2 * NK), dim3(256), 0, stream,
                     w_in, b_in, cb0, cb1, w_out, b_out, dec0, dec1, G, nh, E_swz);
  hipLaunchKernelGGL(rvq_main, dim3(GRID), dim3(256), 0, stream,
                     mel, E_swz, nh, G, dec0, dec1, out);
}